// Round 4
// baseline (79.791 us; speedup 1.0000x reference)
//
#include <hip/hip_runtime.h>
#include <math.h>

#define M_WAVE 32
#define NLEN 8192
#define FFT_N 16384
#define THREADS 1024
#define NPAIR 528   // record count: 32 autos + 496 cross

#define TWOPI_F 6.28318530717958647692f

__device__ __forceinline__ float2 cadd(float2 a, float2 b){return make_float2(a.x+b.x, a.y+b.y);}
__device__ __forceinline__ float2 csub(float2 a, float2 b){return make_float2(a.x-b.x, a.y-b.y);}
__device__ __forceinline__ float2 cmul(float2 a, float2 b){return make_float2(a.x*b.x-a.y*b.y, a.x*b.y+a.y*b.x);}
__device__ __forceinline__ float2 mul_i (float2 a){return make_float2(-a.y,  a.x);}
__device__ __forceinline__ float2 mul_mi(float2 a){return make_float2( a.y, -a.x);}

__device__ __forceinline__ float2 dpp_xor1(float2 v){
    float2 r;
    r.x = __int_as_float(__builtin_amdgcn_mov_dpp(__float_as_int(v.x), 0xB1, 0xF, 0xF, true));
    r.y = __int_as_float(__builtin_amdgcn_mov_dpp(__float_as_int(v.y), 0xB1, 0xF, 0xF, true));
    return r;
}
__device__ __forceinline__ float2 dpp_xor2(float2 v){
    float2 r;
    r.x = __int_as_float(__builtin_amdgcn_mov_dpp(__float_as_int(v.x), 0x4E, 0xF, 0xF, true));
    r.y = __int_as_float(__builtin_amdgcn_mov_dpp(__float_as_int(v.y), 0x4E, 0xF, 0xF, true));
    return r;
}

__device__ __forceinline__ float waveReduceMax(float v) {
    #pragma unroll
    for (int off = 32; off > 0; off >>= 1) v = fmaxf(v, __shfl_down(v, off, 64));
    return v;
}
__device__ __forceinline__ float waveReduceSum(float v) {
    #pragma unroll
    for (int off = 32; off > 0; off >>= 1) v += __shfl_down(v, off, 64);
    return v;
}

// second half of the 16-pt DFT (twiddle + second radix-4 pass), shared
template<int SGN>
__device__ __forceinline__ void dft16_tail(float2 w[16], float2 v[16]){
    const float C1 = 0.923879532511286756f;
    const float S1 = 0.382683432365089772f;
    const float R2 = 0.707106781186547524f;
    const float G = (SGN < 0) ? -1.0f : 1.0f;
    w[5]  = cmul(w[5],  make_float2( C1,  G*S1));
    w[6]  = cmul(w[6],  make_float2( R2,  G*R2));
    w[7]  = cmul(w[7],  make_float2( S1,  G*C1));
    w[9]  = cmul(w[9],  make_float2( R2,  G*R2));
    w[10] = (SGN<0) ? mul_mi(w[10]) : mul_i(w[10]);
    w[11] = cmul(w[11], make_float2(-R2,  G*R2));
    w[13] = cmul(w[13], make_float2( S1,  G*C1));
    w[14] = cmul(w[14], make_float2(-R2,  G*R2));
    w[15] = cmul(w[15], make_float2(-C1, -G*S1));
    #pragma unroll
    for (int k0 = 0; k0 < 4; ++k0){
        float2 a = w[k0*4+0], b = w[k0*4+1], c = w[k0*4+2], d = w[k0*4+3];
        float2 t0 = cadd(a,c), t1 = csub(a,c), t2 = cadd(b,d), t3 = csub(b,d);
        float2 j3 = (SGN < 0) ? mul_mi(t3) : mul_i(t3);
        v[k0]    = cadd(t0,t2);
        v[k0+4]  = cadd(t1,j3);
        v[k0+8]  = csub(t0,t2);
        v[k0+12] = csub(t1,j3);
    }
}

template<int SGN>
__device__ __forceinline__ void dft16(float2 v[16]){
    float2 w[16];
    #pragma unroll
    for (int n0 = 0; n0 < 4; ++n0){
        float2 a = v[n0], b = v[n0+4], c = v[n0+8], d = v[n0+12];
        float2 t0 = cadd(a,c), t1 = csub(a,c), t2 = cadd(b,d), t3 = csub(b,d);
        float2 j3 = (SGN < 0) ? mul_mi(t3) : mul_i(t3);
        w[n0]    = cadd(t0,t2);
        w[4+n0]  = cadd(t1,j3);
        w[8+n0]  = csub(t0,t2);
        w[12+n0] = csub(t1,j3);
    }
    dft16_tail<SGN>(w, v);
}

// forward DFT16 with inputs 8..15 == 0 (zero-padded), SGN=-1
__device__ __forceinline__ void dft16_zero8(float2 v[16]){
    float2 w[16];
    #pragma unroll
    for (int n0 = 0; n0 < 4; ++n0){
        float2 a = v[n0], b = v[n0+4];
        w[n0]    = cadd(a,b);
        w[4+n0]  = make_float2(a.x + b.y, a.y - b.x);  // a - i b
        w[8+n0]  = csub(a,b);
        w[12+n0] = make_float2(a.x - b.y, a.y + b.x);  // a + i b
    }
    dft16_tail<-1>(w, v);
}

template<int SGN>
__device__ __forceinline__ void twchain16(float2 v[16], float theta){
    float th = (SGN < 0) ? -theta : theta;
    float s1,c1; __sincosf(th, &s1, &c1);
    float s4,c4; __sincosf(4.0f*th, &s4, &c4);
    float2 w1 = make_float2(c1,s1), w4 = make_float2(c4,s4);
    float2 lo2 = cmul(w1,w1), lo3 = cmul(lo2,w1);
    float2 hi2 = cmul(w4,w4), hi3 = cmul(hi2,w4);
    float2 lo[4] = {make_float2(1.f,0.f), w1, lo2, lo3};
    float2 hi[4] = {make_float2(1.f,0.f), w4, hi2, hi3};
    #pragma unroll
    for (int s = 1; s < 16; ++s){
        v[s] = cmul(v[s], cmul(hi[s>>2], lo[s&3]));
    }
}

__device__ __forceinline__ int L1swz(int e){
    return (e & ~63) | (((e & 63) + ((e >> 6) & 15)) & 63);
}

// Forward FFT: 128 blocks = 32 m x 4 quarters, 256 threads. Stage A computed
// redundantly (4x) per m; each block keeps 4 chunks, runs B/C (1 wave/chunk).
__global__ __launch_bounds__(256) void fwd_fft_kernel(const float* __restrict__ x,
                                                      float2* __restrict__ spec) {
    __shared__ float2 X4[4096];  // 32 KiB
    const int bx = blockIdx.x, m = bx >> 2, qt = bx & 3;
    const int tid = threadIdx.x;

    // Stage A: 4 columns per thread; keep outputs s = 4qt..4qt+3
    #pragma unroll 1
    for (int cc = 0; cc < 4; ++cc){
        const int j = cc*256 + tid;
        float2 v[16];
        #pragma unroll
        for (int s = 0; s < 8; ++s){
            float ph = TWOPI_F * x[m*NLEN + s*1024 + j];
            float sn,cs; __sincosf(ph,&sn,&cs);
            v[s] = make_float2(cs,sn);
        }
        dft16_zero8(v);
        const float th = TWOPI_F * (float)j / 16384.0f;
        float sb,cb; __sincosf(-(float)(4*qt)*th, &sb, &cb);
        float ss,cs2; __sincosf(-th, &ss, &cs2);
        float2 wcur = make_float2(cb,sb), wstep = make_float2(cs2,ss);
        #pragma unroll
        for (int d = 0; d < 4; ++d){
            X4[d*1024 + L1swz(j)] = cmul(v[4*qt + d], wcur);
            wcur = cmul(wcur, wstep);
        }
    }
    __syncthreads();

    // Stage B: wave w = local chunk w (global chunk 4qt+w)
    const int wv = tid >> 6, jB = tid & 63;
    float2 v[16];
    #pragma unroll
    for (int t = 0; t < 16; ++t) v[t] = X4[wv*1024 + t*64 + ((jB + t) & 63)];
    dft16<-1>(v);
    twchain16<-1>(v, TWOPI_F * (float)jB / 1024.0f);
    #pragma unroll
    for (int sp = 0; sp < 16; ++sp) X4[wv*1024 + sp*64 + ((jB + 4*sp) & 63)] = v[sp];
    __syncthreads();

    // Stage C: per wave, 16 sub-blocks x 4 lanes; DFT16 + tw + 4-lane DPP DFT4
    {
        const int bl = (tid & 63) >> 2, jC = tid & 3;
        #pragma unroll
        for (int a = 0; a < 16; ++a)
            v[a] = X4[wv*1024 + bl*64 + ((4*a + jC + 4*bl) & 63)];
        dft16<-1>(v);
        twchain16<-1>(v, TWOPI_F * (float)jC / 64.0f);
        const bool odd1 = (jC & 1) != 0;
        const bool odd2 = (jC & 2) != 0;
        #pragma unroll
        for (int e = 0; e < 16; ++e){
            float2 p = dpp_xor2(v[e]);
            float2 t = odd2 ? csub(p, v[e]) : cadd(v[e], p);
            float2 q = dpp_xor1(t);
            float2 re = odd1 ? csub(q, t) : cadd(t, q);
            float2 ro = odd1 ? cadd(q, mul_i(t)) : cadd(t, mul_mi(q));
            v[e] = odd2 ? ro : re;
        }
        const int u = ((jC & 1) << 1) | (jC >> 1);
        float4* dst = (float4*)(spec + (size_t)m*FFT_N + (4*qt + wv)*1024 + bl*64 + u*16);
        #pragma unroll
        for (int e = 0; e < 8; ++e)
            dst[e] = make_float4(v[2*e].x, v[2*e].y, v[2*e+1].x, v[2*e+1].y);
    }
}

// Pair kernel: 512 blocks. r<16: packed autos (a=2r, b=2r+1), z = |Sa|^2 + i|Sb|^2.
// r>=16: cross pair (both ordered directions from one IFFT).
__global__ __launch_bounds__(THREADS) void pair_kernel(const float2* __restrict__ spec,
                                                       float4* __restrict__ rec) {
    __shared__ float2 X[FFT_N];     // 128 KiB
    __shared__ float scr[64];
    const int r = blockIdx.x, tid = threadIdx.x;
    const bool packed = (r < 16);
    int a, b;
    if (packed){ a = 2*r; b = 2*r + 1; }
    else {
        int t = r - 16; a = 0; int rem = M_WAVE - 1;
        while (t >= rem){ t -= rem; ++a; rem = M_WAVE - 1 - a; }
        b = a + 1 + t;
    }
    const int blk = tid >> 2, jC = tid & 3;
    const int u = ((jC & 1) << 1) | (jC >> 1);
    float2 v[16];

    // Load spectra, form product (cross: B*conj(A); packed: (|A|^2, |B|^2))
    {
        const float4* pa = (const float4*)(spec + (size_t)a*FFT_N + blk*64 + u*16);
        const float4* pb = (const float4*)(spec + (size_t)b*FFT_N + blk*64 + u*16);
        #pragma unroll
        for (int e = 0; e < 8; ++e){
            float4 A = pa[e], B = pb[e];
            if (packed){
                v[2*e]   = make_float2(A.x*A.x + A.y*A.y, B.x*B.x + B.y*B.y);
                v[2*e+1] = make_float2(A.z*A.z + A.w*A.w, B.z*B.z + B.w*B.w);
            } else {
                v[2*e]   = make_float2(B.x*A.x + B.y*A.y, B.y*A.x - B.x*A.y);
                v[2*e+1] = make_float2(B.z*A.z + B.w*A.w, B.w*A.z - B.z*A.w);
            }
        }
    }
    // Stage C': adjoint lane-DFT4, conj tw W64, DFT16^H, LDS write
    {
        const bool odd1 = (jC & 1) != 0;
        const bool odd2 = (jC & 2) != 0;
        #pragma unroll
        for (int e = 0; e < 16; ++e){
            float2 q = dpp_xor1(v[e]);
            float2 t = odd1 ? csub(q, v[e]) : cadd(v[e], q);
            float2 p = dpp_xor2(t);
            float2 re = odd2 ? csub(p, t) : cadd(t, p);
            float2 ro = odd2 ? csub(p, mul_i(t)) : cadd(t, mul_i(p));
            v[e] = odd1 ? ro : re;
        }
        twchain16<+1>(v, TWOPI_F * (float)jC / 64.0f);
        dft16<+1>(v);
        const int rot = 4*(blk & 15);
        #pragma unroll
        for (int t = 0; t < 16; ++t) X[blk*64 + ((4*t + jC + rot) & 63)] = v[t];
    }
    __syncthreads();
    // Stage B'
    {
        const int sB = tid >> 6, jB = tid & 63;
        #pragma unroll
        for (int sp = 0; sp < 16; ++sp) v[sp] = X[sB*1024 + sp*64 + ((jB + 4*sp) & 63)];
        twchain16<+1>(v, TWOPI_F * (float)jB / 1024.0f);
        dft16<+1>(v);
        #pragma unroll
        for (int t = 0; t < 16; ++t) X[sB*1024 + t*64 + ((jB + t) & 63)] = v[t];
    }
    __syncthreads();
    // Stage A': v[t] = 16384 * sigma[t*1024 + tid]
    {
        const int baseA = L1swz(tid);
        #pragma unroll
        for (int s = 0; s < 16; ++s) v[s] = X[s*1024 + baseA];
        twchain16<+1>(v, TWOPI_F * (float)tid / 16384.0f);
        dft16<+1>(v);
    }

    const float CSCALE = 0.1f / (16384.0f * 16384.0f);
    const float invTN2 = 1.0f / 67108.864f;   // 1/(T*N*N)
    const int lane = tid & 63, wvv = tid >> 6;
    const bool j0 = (tid == 0);

    if (packed){
        // store z, exchange partners z[-n], recover both autos' stats
        __syncthreads();  // A' reads of X complete everywhere before overwrite
        #pragma unroll
        for (int t = 0; t < 16; ++t) X[t*1024 + tid] = v[t];
        __syncthreads();
        float ma = 0.f, mb = 0.f, sa = 0.f, sb = 0.f;
        #pragma unroll
        for (int t = 8; t < 16; ++t){
            const int n = t*1024 + tid;
            const int pn = (FFT_N - n) & (FFT_N - 1);
            float2 z = v[t], zc = X[pn];
            float ar = 0.5f*(z.x + zc.x), ai = 0.5f*(z.y - zc.y);
            float br = 0.5f*(z.x - zc.x), bi = 0.5f*(z.y + zc.y);
            float ua = CSCALE*(ar*ar + ai*ai);
            float ub = CSCALE*(br*br + bi*bi);
            bool valid = !(t == 8 && j0);
            if (valid){
                ma = fmaxf(ma, ua); mb = fmaxf(mb, ub);
                sa += ua; sb += ub;
            }
        }
        float wma = waveReduceMax(ma), wmb = waveReduceMax(mb);
        float wsa = waveReduceSum(sa), wsb = waveReduceSum(sb);
        if (lane == 0){ scr[wvv]=wma; scr[16+wvv]=wmb; scr[32+wvv]=wsa; scr[48+wvv]=wsb; }
        __syncthreads();
        float m_a = scr[0], m_b = scr[16], suma = scr[32], sumb = scr[48];
        #pragma unroll
        for (int i = 1; i < 16; ++i){
            m_a = fmaxf(m_a, scr[i]); m_b = fmaxf(m_b, scr[16+i]);
            suma += scr[32+i]; sumb += scr[48+i];
        }
        __syncthreads();  // done reading scr before reuse
        float lea = 0.f, leb = 0.f;
        #pragma unroll
        for (int t = 8; t < 16; ++t){
            const int n = t*1024 + tid;
            const int pn = (FFT_N - n) & (FFT_N - 1);
            float2 z = v[t], zc = X[pn];
            float ar = 0.5f*(z.x + zc.x), ai = 0.5f*(z.y - zc.y);
            float br = 0.5f*(z.x - zc.x), bi = 0.5f*(z.y + zc.y);
            float ua = CSCALE*(ar*ar + ai*ai);
            float ub = CSCALE*(br*br + bi*bi);
            bool valid = !(t == 8 && j0);
            if (valid){
                lea += __expf((ua - m_a)*invTN2);
                leb += __expf((ub - m_b)*invTN2);
            }
        }
        float wlea = waveReduceSum(lea), wleb = waveReduceSum(leb);
        if (lane == 0){ scr[wvv] = wlea; scr[16+wvv] = wleb; }
        __syncthreads();
        if (tid == 0){
            float ta = 0.f, tb = 0.f;
            #pragma unroll
            for (int i = 0; i < 16; ++i){ ta += scr[i]; tb += scr[16+i]; }
            rec[2*r]   = make_float4(m_a, suma, ta, 0.f);
            rec[2*r+1] = make_float4(m_b, sumb, tb, 0.f);
        }
    } else {
        // cross: lags as in R3 (verified)
        float uval[16];
        float lm = 0.f, lsum = 0.f;
        #pragma unroll
        for (int t = 0; t < 16; ++t){
            float uu = CSCALE * (v[t].x*v[t].x + v[t].y*v[t].y);
            uval[t] = uu;
            bool inv = (t == 8) && j0;
            if (!inv){ lm = fmaxf(lm, uu); lsum += uu; }
            if (t == 0 && j0) lsum += uu;
        }
        float wm = waveReduceMax(lm);
        float wsm = waveReduceSum(lsum);
        if (lane == 0){ scr[wvv] = wm; scr[16+wvv] = wsm; }
        __syncthreads();
        float m_b = scr[0], sumu = scr[16];
        #pragma unroll
        for (int i = 1; i < 16; ++i){ m_b = fmaxf(m_b, scr[i]); sumu += scr[16+i]; }
        __syncthreads();
        float le = 0.f;
        #pragma unroll
        for (int t = 0; t < 16; ++t){
            float ex = __expf((uval[t] - m_b) * invTN2);
            bool inv = (t == 8) && j0;
            if (!inv) le += ((t == 0 && j0) ? 2.f : 1.f) * ex;
        }
        float wle = waveReduceSum(le);
        if (lane == 0) scr[32+wvv] = wle;
        __syncthreads();
        if (tid == 0){
            float sb2 = 0.f;
            #pragma unroll
            for (int i = 0; i < 16; ++i) sb2 += scr[32+i];
            rec[16 + r] = make_float4(m_b, sumu, sb2, 0.f);  // rec[32 + (r-16)]
        }
    }
}

// Merge 528 records -> 7 outputs.
__global__ __launch_bounds__(256) void final_kernel(const float4* __restrict__ rec,
                                                    float* __restrict__ out) {
    __shared__ float smA[256], smC[256];
    __shared__ double sS[256], sA[256], sC[256];
    const int tid = threadIdx.x;

    float mA = 0.f, mC = 0.f;
    for (int r = tid; r < NPAIR; r += 256){
        float mx = rec[r].x;
        if (r < M_WAVE) mA = fmaxf(mA, mx); else mC = fmaxf(mC, mx);
    }
    smA[tid] = mA; smC[tid] = mC;
    __syncthreads();
    for (int s = 128; s > 0; s >>= 1){
        if (tid < s){ smA[tid]=fmaxf(smA[tid],smA[tid+s]); smC[tid]=fmaxf(smC[tid],smC[tid+s]); }
        __syncthreads();
    }
    const float maxA_g = smA[0], maxC_g = smC[0];
    const float Mall = fmaxf(maxA_g, maxC_g);

    const double invTN2 = 1.0/67108.864;
    double S = 0.0, sumA = 0.0, sumC = 0.0;
    for (int r = tid; r < NPAIR; r += 256){
        float4 rv = rec[r];
        S += (double)rv.z * exp(((double)rv.x - (double)Mall)*invTN2);
        if (r < M_WAVE) sumA += (double)rv.y; else sumC += (double)rv.y;
    }
    sS[tid]=S; sA[tid]=sumA; sC[tid]=sumC;
    __syncthreads();
    for (int s = 128; s > 0; s >>= 1){
        if (tid < s){ sS[tid]+=sS[tid+s]; sA[tid]+=sA[tid+s]; sC[tid]+=sC[tid+s]; }
        __syncthreads();
    }
    if (tid == 0){
        const double invN2 = 1.0/67108864.0;
        out[0] = (float)((double)Mall*invN2 + 1e-3*log(sS[0]));
        out[1] = (float)((double)Mall*invN2);
        out[2] = maxA_g;
        out[3] = maxC_g;
        out[4] = (float)((sA[0]+sC[0])*invN2);
        out[5] = (float)sA[0];
        out[6] = (float)sC[0];
    }
}

extern "C" void kernel_launch(void* const* d_in, const int* in_sizes, int n_in,
                              void* d_out, int out_size, void* d_ws, size_t ws_size,
                              hipStream_t stream) {
    (void)in_sizes; (void)n_in; (void)out_size; (void)ws_size;
    const float* x = (const float*)d_in[0];
    float* out = (float*)d_out;

    float2* spec = (float2*)d_ws;
    float4* rec = (float4*)((char*)d_ws + (size_t)M_WAVE * FFT_N * sizeof(float2));

    fwd_fft_kernel<<<128, 256, 0, stream>>>(x, spec);
    pair_kernel<<<512, THREADS, 0, stream>>>(spec, rec);
    final_kernel<<<1, 256, 0, stream>>>(rec, out);
}

// Round 5
// 70.061 us; speedup vs baseline: 1.1389x; 1.1389x over previous
//
#include <hip/hip_runtime.h>
#include <math.h>

#define M_WAVE 32
#define NLEN 8192
#define FFT_N 16384
#define THREADS 1024
#define NPAIR 528   // 496 cross (blocks 0..495) + 32 autos (blocks 496..527)

#define TWOPI_F 6.28318530717958647692f

__device__ __forceinline__ float2 cadd(float2 a, float2 b){return make_float2(a.x+b.x, a.y+b.y);}
__device__ __forceinline__ float2 csub(float2 a, float2 b){return make_float2(a.x-b.x, a.y-b.y);}
__device__ __forceinline__ float2 cmul(float2 a, float2 b){return make_float2(a.x*b.x-a.y*b.y, a.x*b.y+a.y*b.x);}
__device__ __forceinline__ float2 mul_i (float2 a){return make_float2(-a.y,  a.x);}
__device__ __forceinline__ float2 mul_mi(float2 a){return make_float2( a.y, -a.x);}

__device__ __forceinline__ float2 dpp_xor1(float2 v){
    float2 r;
    r.x = __int_as_float(__builtin_amdgcn_mov_dpp(__float_as_int(v.x), 0xB1, 0xF, 0xF, true));
    r.y = __int_as_float(__builtin_amdgcn_mov_dpp(__float_as_int(v.y), 0xB1, 0xF, 0xF, true));
    return r;
}
__device__ __forceinline__ float2 dpp_xor2(float2 v){
    float2 r;
    r.x = __int_as_float(__builtin_amdgcn_mov_dpp(__float_as_int(v.x), 0x4E, 0xF, 0xF, true));
    r.y = __int_as_float(__builtin_amdgcn_mov_dpp(__float_as_int(v.y), 0x4E, 0xF, 0xF, true));
    return r;
}

__device__ __forceinline__ float waveReduceMax(float v) {
    #pragma unroll
    for (int off = 32; off > 0; off >>= 1) v = fmaxf(v, __shfl_down(v, off, 64));
    return v;
}
__device__ __forceinline__ float waveReduceSum(float v) {
    #pragma unroll
    for (int off = 32; off > 0; off >>= 1) v += __shfl_down(v, off, 64);
    return v;
}

// second half of the 16-pt DFT (twiddle + second radix-4 pass), shared
template<int SGN>
__device__ __forceinline__ void dft16_tail(float2 w[16], float2 v[16]){
    const float C1 = 0.923879532511286756f;
    const float S1 = 0.382683432365089772f;
    const float R2 = 0.707106781186547524f;
    const float G = (SGN < 0) ? -1.0f : 1.0f;
    w[5]  = cmul(w[5],  make_float2( C1,  G*S1));
    w[6]  = cmul(w[6],  make_float2( R2,  G*R2));
    w[7]  = cmul(w[7],  make_float2( S1,  G*C1));
    w[9]  = cmul(w[9],  make_float2( R2,  G*R2));
    w[10] = (SGN<0) ? mul_mi(w[10]) : mul_i(w[10]);
    w[11] = cmul(w[11], make_float2(-R2,  G*R2));
    w[13] = cmul(w[13], make_float2( S1,  G*C1));
    w[14] = cmul(w[14], make_float2(-R2,  G*R2));
    w[15] = cmul(w[15], make_float2(-C1, -G*S1));
    #pragma unroll
    for (int k0 = 0; k0 < 4; ++k0){
        float2 a = w[k0*4+0], b = w[k0*4+1], c = w[k0*4+2], d = w[k0*4+3];
        float2 t0 = cadd(a,c), t1 = csub(a,c), t2 = cadd(b,d), t3 = csub(b,d);
        float2 j3 = (SGN < 0) ? mul_mi(t3) : mul_i(t3);
        v[k0]    = cadd(t0,t2);
        v[k0+4]  = cadd(t1,j3);
        v[k0+8]  = csub(t0,t2);
        v[k0+12] = csub(t1,j3);
    }
}

template<int SGN>
__device__ __forceinline__ void dft16(float2 v[16]){
    float2 w[16];
    #pragma unroll
    for (int n0 = 0; n0 < 4; ++n0){
        float2 a = v[n0], b = v[n0+4], c = v[n0+8], d = v[n0+12];
        float2 t0 = cadd(a,c), t1 = csub(a,c), t2 = cadd(b,d), t3 = csub(b,d);
        float2 j3 = (SGN < 0) ? mul_mi(t3) : mul_i(t3);
        w[n0]    = cadd(t0,t2);
        w[4+n0]  = cadd(t1,j3);
        w[8+n0]  = csub(t0,t2);
        w[12+n0] = csub(t1,j3);
    }
    dft16_tail<SGN>(w, v);
}

// forward DFT16 with inputs 8..15 == 0 (zero-padded), SGN=-1
__device__ __forceinline__ void dft16_zero8(float2 v[16]){
    float2 w[16];
    #pragma unroll
    for (int n0 = 0; n0 < 4; ++n0){
        float2 a = v[n0], b = v[n0+4];
        w[n0]    = cadd(a,b);
        w[4+n0]  = make_float2(a.x + b.y, a.y - b.x);  // a - i b
        w[8+n0]  = csub(a,b);
        w[12+n0] = make_float2(a.x - b.y, a.y + b.x);  // a + i b
    }
    dft16_tail<-1>(w, v);
}

template<int SGN>
__device__ __forceinline__ void twchain16(float2 v[16], float theta){
    float th = (SGN < 0) ? -theta : theta;
    float s1,c1; __sincosf(th, &s1, &c1);
    float s4,c4; __sincosf(4.0f*th, &s4, &c4);
    float2 w1 = make_float2(c1,s1), w4 = make_float2(c4,s4);
    float2 lo2 = cmul(w1,w1), lo3 = cmul(lo2,w1);
    float2 hi2 = cmul(w4,w4), hi3 = cmul(hi2,w4);
    float2 lo[4] = {make_float2(1.f,0.f), w1, lo2, lo3};
    float2 hi[4] = {make_float2(1.f,0.f), w4, hi2, hi3};
    #pragma unroll
    for (int s = 1; s < 16; ++s){
        v[s] = cmul(v[s], cmul(hi[s>>2], lo[s&3]));
    }
}

__device__ __forceinline__ int L1swz(int e){
    return (e & ~63) | (((e & 63) + ((e >> 6) & 15)) & 63);
}

// Forward FFT (R4 version, verified): 128 blocks = 32 m x 4 quarters, 256 threads.
__global__ __launch_bounds__(256) void fwd_fft_kernel(const float* __restrict__ x,
                                                      float2* __restrict__ spec) {
    __shared__ float2 X4[4096];  // 32 KiB
    const int bx = blockIdx.x, m = bx >> 2, qt = bx & 3;
    const int tid = threadIdx.x;

    // Stage A: 4 columns per thread; keep outputs s = 4qt..4qt+3
    #pragma unroll 1
    for (int cc = 0; cc < 4; ++cc){
        const int j = cc*256 + tid;
        float2 v[16];
        #pragma unroll
        for (int s = 0; s < 8; ++s){
            float ph = TWOPI_F * x[m*NLEN + s*1024 + j];
            float sn,cs; __sincosf(ph,&sn,&cs);
            v[s] = make_float2(cs,sn);
        }
        dft16_zero8(v);
        const float th = TWOPI_F * (float)j / 16384.0f;
        float sb,cb; __sincosf(-(float)(4*qt)*th, &sb, &cb);
        float ss,cs2; __sincosf(-th, &ss, &cs2);
        float2 wcur = make_float2(cb,sb), wstep = make_float2(cs2,ss);
        #pragma unroll
        for (int d = 0; d < 4; ++d){
            X4[d*1024 + L1swz(j)] = cmul(v[4*qt + d], wcur);
            wcur = cmul(wcur, wstep);
        }
    }
    __syncthreads();

    // Stage B: wave w = local chunk w (global chunk 4qt+w)
    const int wv = tid >> 6, jB = tid & 63;
    float2 v[16];
    #pragma unroll
    for (int t = 0; t < 16; ++t) v[t] = X4[wv*1024 + t*64 + ((jB + t) & 63)];
    dft16<-1>(v);
    twchain16<-1>(v, TWOPI_F * (float)jB / 1024.0f);
    #pragma unroll
    for (int sp = 0; sp < 16; ++sp) X4[wv*1024 + sp*64 + ((jB + 4*sp) & 63)] = v[sp];
    __syncthreads();

    // Stage C: per wave, 16 sub-blocks x 4 lanes; DFT16 + tw + 4-lane DPP DFT4
    {
        const int bl = (tid & 63) >> 2, jC = tid & 3;
        #pragma unroll
        for (int a = 0; a < 16; ++a)
            v[a] = X4[wv*1024 + bl*64 + ((4*a + jC + 4*bl) & 63)];
        dft16<-1>(v);
        twchain16<-1>(v, TWOPI_F * (float)jC / 64.0f);
        const bool odd1 = (jC & 1) != 0;
        const bool odd2 = (jC & 2) != 0;
        #pragma unroll
        for (int e = 0; e < 16; ++e){
            float2 p = dpp_xor2(v[e]);
            float2 t = odd2 ? csub(p, v[e]) : cadd(v[e], p);
            float2 q = dpp_xor1(t);
            float2 re = odd1 ? csub(q, t) : cadd(t, q);
            float2 ro = odd1 ? cadd(q, mul_i(t)) : cadd(t, mul_mi(q));
            v[e] = odd2 ? ro : re;
        }
        const int u = ((jC & 1) << 1) | (jC >> 1);
        float4* dst = (float4*)(spec + (size_t)m*FFT_N + (4*qt + wv)*1024 + bl*64 + u*16);
        #pragma unroll
        for (int e = 0; e < 8; ++e)
            dst[e] = make_float4(v[2*e].x, v[2*e].y, v[2*e+1].x, v[2*e+1].y);
    }
}

// Pair kernel (R3 version, verified 49.4us): cross pairs first (blocks 0..495),
// autos last (496..527) so the 16-block scheduling tail is the cheap autos.
__global__ __launch_bounds__(THREADS) void pair_kernel(const float2* __restrict__ spec,
                                                       float4* __restrict__ rec) {
    __shared__ float2 X[FFT_N];  // 128 KiB
    const int r = blockIdx.x, tid = threadIdx.x;
    const bool is_auto = (r >= 496);
    int a, b, rec_idx;
    if (is_auto){
        a = b = r - 496;
        rec_idx = r - 496;           // autos -> rec[0..31]
    } else {
        int t = r; a = 0; int rem = M_WAVE - 1;
        while (t >= rem){ t -= rem; ++a; rem = M_WAVE - 1 - a; }
        b = a + 1 + t;
        rec_idx = M_WAVE + r;        // cross -> rec[32..527]
    }
    const int blk = tid >> 2, jC = tid & 3;
    const int u = ((jC & 1) << 1) | (jC >> 1);
    float2 v[16];

    // Load both spectra (coalesced float4), product B*conj(A)
    {
        const float4* pa = (const float4*)(spec + (size_t)a*FFT_N + blk*64 + u*16);
        const float4* pb = (const float4*)(spec + (size_t)b*FFT_N + blk*64 + u*16);
        #pragma unroll
        for (int e = 0; e < 8; ++e){
            float4 A = pa[e], B = pb[e];
            v[2*e]   = make_float2(B.x*A.x + B.y*A.y, B.y*A.x - B.x*A.y);
            v[2*e+1] = make_float2(B.z*A.z + B.w*A.w, B.w*A.z - B.z*A.w);
        }
    }
    // Stage C': adjoint lane-DFT4, conj twiddle W64, DFT16^H, LDS write
    {
        const bool odd1 = (jC & 1) != 0;
        const bool odd2 = (jC & 2) != 0;
        #pragma unroll
        for (int e = 0; e < 16; ++e){
            float2 q = dpp_xor1(v[e]);
            float2 t = odd1 ? csub(q, v[e]) : cadd(v[e], q);
            float2 p = dpp_xor2(t);
            float2 re = odd2 ? csub(p, t) : cadd(t, p);
            float2 ro = odd2 ? csub(p, mul_i(t)) : cadd(t, mul_i(p));
            v[e] = odd1 ? ro : re;
        }
        twchain16<+1>(v, TWOPI_F * (float)jC / 64.0f);
        dft16<+1>(v);
        const int rot = blk & 15;
        #pragma unroll
        for (int t = 0; t < 16; ++t) X[blk*64 + ((4*t + jC + rot) & 63)] = v[t];
    }
    __syncthreads();
    // Stage B'
    {
        const int sB = tid >> 6, jB = tid & 63;
        #pragma unroll
        for (int sp = 0; sp < 16; ++sp) v[sp] = X[sB*1024 + sp*64 + ((jB + sp) & 63)];
        twchain16<+1>(v, TWOPI_F * (float)jB / 1024.0f);
        dft16<+1>(v);
        #pragma unroll
        for (int t = 0; t < 16; ++t) X[sB*1024 + t*64 + ((jB + t) & 63)] = v[t];
    }
    __syncthreads();
    // Stage A': v[t] = 16384 * sigma[t*1024 + tid]
    {
        const int baseA = L1swz(tid);
        #pragma unroll
        for (int s = 0; s < 16; ++s) v[s] = X[s*1024 + baseA];
        twchain16<+1>(v, TWOPI_F * (float)tid / 16384.0f);
        dft16<+1>(v);
    }

    // Stats. Lags: auto uses n in [N+1, 2N-1]; cross uses all n except N, n=0 double.
    const float CSCALE = 0.1f / (16384.0f * 16384.0f);
    const bool j0 = (tid == 0);
    float uval[16];
    float lm = 0.f, lsum = 0.f;
    #pragma unroll
    for (int t = 0; t < 16; ++t){
        float uu = CSCALE * (v[t].x*v[t].x + v[t].y*v[t].y);
        uval[t] = uu;
        if (is_auto){
            bool valid = (t > 8) || ((t == 8) && !j0);
            if (valid){ lm = fmaxf(lm, uu); lsum += uu; }
        } else {
            bool inv = (t == 8) && j0;
            if (!inv){ lm = fmaxf(lm, uu); lsum += uu; }
            if (t == 0 && j0) lsum += uu;
        }
    }
    __syncthreads();  // X reads done; reuse as scratch

    float* scratch = (float*)X;
    const int lane = tid & 63, wvv = tid >> 6;
    float wm = waveReduceMax(lm);
    float wsm = waveReduceSum(lsum);
    if (lane == 0){ scratch[wvv] = wm; scratch[16+wvv] = wsm; }
    __syncthreads();
    float m_b = scratch[0], sumu = scratch[16];
    #pragma unroll
    for (int i = 1; i < 16; ++i){ m_b = fmaxf(m_b, scratch[i]); sumu += scratch[16+i]; }

    const float invTN2 = 1.0f / 67108.864f;   // 1/(T*N*N)
    float le = 0.f;
    #pragma unroll
    for (int t = 0; t < 16; ++t){
        float ex = __expf((uval[t] - m_b) * invTN2);
        if (is_auto){
            bool valid = (t > 8) || ((t == 8) && !j0);
            if (valid) le += ex;
        } else {
            bool inv = (t == 8) && j0;
            if (!inv) le += ((t == 0 && j0) ? 2.f : 1.f) * ex;
        }
    }
    float wle = waveReduceSum(le);
    if (lane == 0) scratch[32+wvv] = wle;
    __syncthreads();
    if (tid == 0){
        float sb2 = 0.f;
        #pragma unroll
        for (int i = 0; i < 16; ++i) sb2 += scratch[32+i];
        rec[rec_idx] = make_float4(m_b, sumu, sb2, 0.f);
    }
}

// Merge 528 records -> 7 outputs. Autos at rec[0..31], cross at rec[32..527].
__global__ __launch_bounds__(256) void final_kernel(const float4* __restrict__ rec,
                                                    float* __restrict__ out) {
    __shared__ float smA[256], smC[256];
    __shared__ double sS[256], sA[256], sC[256];
    const int tid = threadIdx.x;

    float mA = 0.f, mC = 0.f;
    for (int r = tid; r < NPAIR; r += 256){
        float mx = rec[r].x;
        if (r < M_WAVE) mA = fmaxf(mA, mx); else mC = fmaxf(mC, mx);
    }
    smA[tid] = mA; smC[tid] = mC;
    __syncthreads();
    for (int s = 128; s > 0; s >>= 1){
        if (tid < s){ smA[tid]=fmaxf(smA[tid],smA[tid+s]); smC[tid]=fmaxf(smC[tid],smC[tid+s]); }
        __syncthreads();
    }
    const float maxA_g = smA[0], maxC_g = smC[0];
    const float Mall = fmaxf(maxA_g, maxC_g);

    const double invTN2 = 1.0/67108.864;
    double S = 0.0, sumA = 0.0, sumC = 0.0;
    for (int r = tid; r < NPAIR; r += 256){
        float4 rv = rec[r];
        S += (double)rv.z * exp(((double)rv.x - (double)Mall)*invTN2);
        if (r < M_WAVE) sumA += (double)rv.y; else sumC += (double)rv.y;
    }
    sS[tid]=S; sA[tid]=sumA; sC[tid]=sumC;
    __syncthreads();
    for (int s = 128; s > 0; s >>= 1){
        if (tid < s){ sS[tid]+=sS[tid+s]; sA[tid]+=sA[tid+s]; sC[tid]+=sC[tid+s]; }
        __syncthreads();
    }
    if (tid == 0){
        const double invN2 = 1.0/67108864.0;
        out[0] = (float)((double)Mall*invN2 + 1e-3*log(sS[0]));
        out[1] = (float)((double)Mall*invN2);
        out[2] = maxA_g;
        out[3] = maxC_g;
        out[4] = (float)((sA[0]+sC[0])*invN2);
        out[5] = (float)sA[0];
        out[6] = (float)sC[0];
    }
}

extern "C" void kernel_launch(void* const* d_in, const int* in_sizes, int n_in,
                              void* d_out, int out_size, void* d_ws, size_t ws_size,
                              hipStream_t stream) {
    (void)in_sizes; (void)n_in; (void)out_size; (void)ws_size;
    const float* x = (const float*)d_in[0];
    float* out = (float*)d_out;

    float2* spec = (float2*)d_ws;
    float4* rec = (float4*)((char*)d_ws + (size_t)M_WAVE * FFT_N * sizeof(float2));

    fwd_fft_kernel<<<128, 256, 0, stream>>>(x, spec);
    pair_kernel<<<NPAIR, THREADS, 0, stream>>>(spec, rec);
    final_kernel<<<1, 256, 0, stream>>>(rec, out);
}

// Round 6
// 68.044 us; speedup vs baseline: 1.1726x; 1.0296x over previous
//
#include <hip/hip_runtime.h>
#include <math.h>

#define M_WAVE 32
#define NLEN 8192
#define FFT_N 16384
#define THREADS 1024
#define NPAIR 528   // 496 cross (blocks 0..495) + 32 autos (blocks 496..527)

#define TWOPI_F 6.28318530717958647692f

__device__ __forceinline__ float2 cadd(float2 a, float2 b){return make_float2(a.x+b.x, a.y+b.y);}
__device__ __forceinline__ float2 csub(float2 a, float2 b){return make_float2(a.x-b.x, a.y-b.y);}
__device__ __forceinline__ float2 cmul(float2 a, float2 b){return make_float2(a.x*b.x-a.y*b.y, a.x*b.y+a.y*b.x);}
__device__ __forceinline__ float2 mul_i (float2 a){return make_float2(-a.y,  a.x);}
__device__ __forceinline__ float2 mul_mi(float2 a){return make_float2( a.y, -a.x);}

__device__ __forceinline__ float2 dpp_xor1(float2 v){
    float2 r;
    r.x = __int_as_float(__builtin_amdgcn_mov_dpp(__float_as_int(v.x), 0xB1, 0xF, 0xF, true));
    r.y = __int_as_float(__builtin_amdgcn_mov_dpp(__float_as_int(v.y), 0xB1, 0xF, 0xF, true));
    return r;
}
__device__ __forceinline__ float2 dpp_xor2(float2 v){
    float2 r;
    r.x = __int_as_float(__builtin_amdgcn_mov_dpp(__float_as_int(v.x), 0x4E, 0xF, 0xF, true));
    r.y = __int_as_float(__builtin_amdgcn_mov_dpp(__float_as_int(v.y), 0x4E, 0xF, 0xF, true));
    return r;
}

__device__ __forceinline__ float waveReduceMax(float v) {
    #pragma unroll
    for (int off = 32; off > 0; off >>= 1) v = fmaxf(v, __shfl_down(v, off, 64));
    return v;
}
__device__ __forceinline__ float waveReduceSum(float v) {
    #pragma unroll
    for (int off = 32; off > 0; off >>= 1) v += __shfl_down(v, off, 64);
    return v;
}

// second half of the 16-pt DFT (twiddle + second radix-4 pass), shared
template<int SGN>
__device__ __forceinline__ void dft16_tail(float2 w[16], float2 v[16]){
    const float C1 = 0.923879532511286756f;
    const float S1 = 0.382683432365089772f;
    const float R2 = 0.707106781186547524f;
    const float G = (SGN < 0) ? -1.0f : 1.0f;
    w[5]  = cmul(w[5],  make_float2( C1,  G*S1));
    w[6]  = cmul(w[6],  make_float2( R2,  G*R2));
    w[7]  = cmul(w[7],  make_float2( S1,  G*C1));
    w[9]  = cmul(w[9],  make_float2( R2,  G*R2));
    w[10] = (SGN<0) ? mul_mi(w[10]) : mul_i(w[10]);
    w[11] = cmul(w[11], make_float2(-R2,  G*R2));
    w[13] = cmul(w[13], make_float2( S1,  G*C1));
    w[14] = cmul(w[14], make_float2(-R2,  G*R2));
    w[15] = cmul(w[15], make_float2(-C1, -G*S1));
    #pragma unroll
    for (int k0 = 0; k0 < 4; ++k0){
        float2 a = w[k0*4+0], b = w[k0*4+1], c = w[k0*4+2], d = w[k0*4+3];
        float2 t0 = cadd(a,c), t1 = csub(a,c), t2 = cadd(b,d), t3 = csub(b,d);
        float2 j3 = (SGN < 0) ? mul_mi(t3) : mul_i(t3);
        v[k0]    = cadd(t0,t2);
        v[k0+4]  = cadd(t1,j3);
        v[k0+8]  = csub(t0,t2);
        v[k0+12] = csub(t1,j3);
    }
}

template<int SGN>
__device__ __forceinline__ void dft16(float2 v[16]){
    float2 w[16];
    #pragma unroll
    for (int n0 = 0; n0 < 4; ++n0){
        float2 a = v[n0], b = v[n0+4], c = v[n0+8], d = v[n0+12];
        float2 t0 = cadd(a,c), t1 = csub(a,c), t2 = cadd(b,d), t3 = csub(b,d);
        float2 j3 = (SGN < 0) ? mul_mi(t3) : mul_i(t3);
        w[n0]    = cadd(t0,t2);
        w[4+n0]  = cadd(t1,j3);
        w[8+n0]  = csub(t0,t2);
        w[12+n0] = csub(t1,j3);
    }
    dft16_tail<SGN>(w, v);
}

// forward DFT16 with inputs 8..15 == 0 (zero-padded), SGN=-1
__device__ __forceinline__ void dft16_zero8(float2 v[16]){
    float2 w[16];
    #pragma unroll
    for (int n0 = 0; n0 < 4; ++n0){
        float2 a = v[n0], b = v[n0+4];
        w[n0]    = cadd(a,b);
        w[4+n0]  = make_float2(a.x + b.y, a.y - b.x);  // a - i b
        w[8+n0]  = csub(a,b);
        w[12+n0] = make_float2(a.x - b.y, a.y + b.x);  // a + i b
    }
    dft16_tail<-1>(w, v);
}

template<int SGN>
__device__ __forceinline__ void twchain16(float2 v[16], float theta){
    float th = (SGN < 0) ? -theta : theta;
    float s1,c1; __sincosf(th, &s1, &c1);
    float s4,c4; __sincosf(4.0f*th, &s4, &c4);
    float2 w1 = make_float2(c1,s1), w4 = make_float2(c4,s4);
    float2 lo2 = cmul(w1,w1), lo3 = cmul(lo2,w1);
    float2 hi2 = cmul(w4,w4), hi3 = cmul(hi2,w4);
    float2 lo[4] = {make_float2(1.f,0.f), w1, lo2, lo3};
    float2 hi[4] = {make_float2(1.f,0.f), w4, hi2, hi3};
    #pragma unroll
    for (int s = 1; s < 16; ++s){
        v[s] = cmul(v[s], cmul(hi[s>>2], lo[s&3]));
    }
}

__device__ __forceinline__ int L1swz(int e){
    return (e & ~63) | (((e & 63) + ((e >> 6) & 15)) & 63);
}

// Forward FFT: 128 blocks = 32 m x 4 quarters, 256 threads.
// launch_bounds(256,1): 1 wave/SIMD anyway (grid covers 128 CUs at 1 block) --
// give the compiler the full VGPR file for ILP across the 16 element chains.
__global__ __launch_bounds__(256, 1) void fwd_fft_kernel(const float* __restrict__ x,
                                                         float2* __restrict__ spec) {
    __shared__ float2 X4[4096];  // 32 KiB
    const int bx = blockIdx.x, m = bx >> 2, qt = bx & 3;
    const int tid = threadIdx.x;

    // Stage A: 4 columns per thread; keep outputs s = 4qt..4qt+3
    #pragma unroll 1
    for (int cc = 0; cc < 4; ++cc){
        const int j = cc*256 + tid;
        float2 v[16];
        #pragma unroll
        for (int s = 0; s < 8; ++s){
            float ph = TWOPI_F * x[m*NLEN + s*1024 + j];
            float sn,cs; __sincosf(ph,&sn,&cs);
            v[s] = make_float2(cs,sn);
        }
        dft16_zero8(v);
        const float th = TWOPI_F * (float)j / 16384.0f;
        float sb,cb; __sincosf(-(float)(4*qt)*th, &sb, &cb);
        float ss,cs2; __sincosf(-th, &ss, &cs2);
        float2 wcur = make_float2(cb,sb), wstep = make_float2(cs2,ss);
        #pragma unroll
        for (int d = 0; d < 4; ++d){
            X4[d*1024 + L1swz(j)] = cmul(v[4*qt + d], wcur);
            wcur = cmul(wcur, wstep);
        }
    }
    __syncthreads();   // cross-wave: every thread wrote into all 4 chunks

    // Stage B: wave w = local chunk w (global chunk 4qt+w). Wave-local.
    const int wv = tid >> 6, jB = tid & 63;
    float2 v[16];
    #pragma unroll
    for (int t = 0; t < 16; ++t) v[t] = X4[wv*1024 + t*64 + ((jB + t) & 63)];
    dft16<-1>(v);
    twchain16<-1>(v, TWOPI_F * (float)jB / 1024.0f);
    #pragma unroll
    for (int sp = 0; sp < 16; ++sp) X4[wv*1024 + sp*64 + ((jB + 4*sp) & 63)] = v[sp];
    // no barrier: stage C reads only this wave's chunk (DS pipe is in-order per wave)

    // Stage C: per wave, 16 sub-blocks x 4 lanes; DFT16 + tw + 4-lane DPP DFT4
    {
        const int bl = (tid & 63) >> 2, jC = tid & 3;
        #pragma unroll
        for (int a = 0; a < 16; ++a)
            v[a] = X4[wv*1024 + bl*64 + ((4*a + jC + 4*bl) & 63)];
        dft16<-1>(v);
        twchain16<-1>(v, TWOPI_F * (float)jC / 64.0f);
        const bool odd1 = (jC & 1) != 0;
        const bool odd2 = (jC & 2) != 0;
        #pragma unroll
        for (int e = 0; e < 16; ++e){
            float2 p = dpp_xor2(v[e]);
            float2 t = odd2 ? csub(p, v[e]) : cadd(v[e], p);
            float2 q = dpp_xor1(t);
            float2 re = odd1 ? csub(q, t) : cadd(t, q);
            float2 ro = odd1 ? cadd(q, mul_i(t)) : cadd(t, mul_mi(q));
            v[e] = odd2 ? ro : re;
        }
        const int u = ((jC & 1) << 1) | (jC >> 1);
        float4* dst = (float4*)(spec + (size_t)m*FFT_N + (4*qt + wv)*1024 + bl*64 + u*16);
        #pragma unroll
        for (int e = 0; e < 8; ++e)
            dst[e] = make_float4(v[2*e].x, v[2*e].y, v[2*e+1].x, v[2*e+1].y);
    }
}

// Pair kernel. launch_bounds(1024,4): LDS caps at 1 block/CU = 4 waves/EU, so a
// 128-VGPR budget is free -- lets the compiler keep v[16]+w[16] live (ILP).
// C'/B' swizzle = R4's conflict-free map (2-way max). C'->B' barrier removed
// (wave-local exchange). Cross pairs blocks 0..495, autos last (cheap tail).
__global__ __launch_bounds__(THREADS, 4) void pair_kernel(const float2* __restrict__ spec,
                                                          float4* __restrict__ rec) {
    __shared__ float2 X[FFT_N];  // 128 KiB
    const int r = blockIdx.x, tid = threadIdx.x;
    const bool is_auto = (r >= 496);
    int a, b, rec_idx;
    if (is_auto){
        a = b = r - 496;
        rec_idx = r - 496;           // autos -> rec[0..31]
    } else {
        int t = r; a = 0; int rem = M_WAVE - 1;
        while (t >= rem){ t -= rem; ++a; rem = M_WAVE - 1 - a; }
        b = a + 1 + t;
        rec_idx = M_WAVE + r;        // cross -> rec[32..527]
    }
    const int blk = tid >> 2, jC = tid & 3;
    const int u = ((jC & 1) << 1) | (jC >> 1);
    float2 v[16];

    // Load both spectra (coalesced float4), product B*conj(A)
    {
        const float4* pa = (const float4*)(spec + (size_t)a*FFT_N + blk*64 + u*16);
        const float4* pb = (const float4*)(spec + (size_t)b*FFT_N + blk*64 + u*16);
        #pragma unroll
        for (int e = 0; e < 8; ++e){
            float4 A = pa[e], B = pb[e];
            v[2*e]   = make_float2(B.x*A.x + B.y*A.y, B.y*A.x - B.x*A.y);
            v[2*e+1] = make_float2(B.z*A.z + B.w*A.w, B.w*A.z - B.z*A.w);
        }
    }
    // Stage C': adjoint lane-DFT4, conj twiddle W64, DFT16^H, LDS write
    {
        const bool odd1 = (jC & 1) != 0;
        const bool odd2 = (jC & 2) != 0;
        #pragma unroll
        for (int e = 0; e < 16; ++e){
            float2 q = dpp_xor1(v[e]);
            float2 t = odd1 ? csub(q, v[e]) : cadd(v[e], q);
            float2 p = dpp_xor2(t);
            float2 re = odd2 ? csub(p, t) : cadd(t, p);
            float2 ro = odd2 ? csub(p, mul_i(t)) : cadd(t, mul_i(p));
            v[e] = odd1 ? ro : re;
        }
        twchain16<+1>(v, TWOPI_F * (float)jC / 64.0f);
        dft16<+1>(v);
        const int rot = 4*(blk & 15);
        #pragma unroll
        for (int t = 0; t < 16; ++t) X[blk*64 + ((4*t + jC + rot) & 63)] = v[t];
    }
    // no barrier: B' reads only this wave's chunk
    // Stage B'
    {
        const int sB = tid >> 6, jB = tid & 63;
        #pragma unroll
        for (int sp = 0; sp < 16; ++sp) v[sp] = X[sB*1024 + sp*64 + ((jB + 4*sp) & 63)];
        twchain16<+1>(v, TWOPI_F * (float)jB / 1024.0f);
        dft16<+1>(v);
        #pragma unroll
        for (int t = 0; t < 16; ++t) X[sB*1024 + t*64 + ((jB + t) & 63)] = v[t];
    }
    __syncthreads();   // cross-wave: A' gathers from all chunks
    // Stage A': v[t] = 16384 * sigma[t*1024 + tid]
    {
        const int baseA = L1swz(tid);
        #pragma unroll
        for (int s = 0; s < 16; ++s) v[s] = X[s*1024 + baseA];
        twchain16<+1>(v, TWOPI_F * (float)tid / 16384.0f);
        dft16<+1>(v);
    }

    // Stats. Lags: auto uses n in [N+1, 2N-1]; cross uses all n except N, n=0 double.
    const float CSCALE = 0.1f / (16384.0f * 16384.0f);
    const bool j0 = (tid == 0);
    float uval[16];
    float lm = 0.f, lsum = 0.f;
    #pragma unroll
    for (int t = 0; t < 16; ++t){
        float uu = CSCALE * (v[t].x*v[t].x + v[t].y*v[t].y);
        uval[t] = uu;
        if (is_auto){
            bool valid = (t > 8) || ((t == 8) && !j0);
            if (valid){ lm = fmaxf(lm, uu); lsum += uu; }
        } else {
            bool inv = (t == 8) && j0;
            if (!inv){ lm = fmaxf(lm, uu); lsum += uu; }
            if (t == 0 && j0) lsum += uu;
        }
    }
    __syncthreads();  // X reads done; reuse as scratch

    float* scratch = (float*)X;
    const int lane = tid & 63, wvv = tid >> 6;
    float wm = waveReduceMax(lm);
    float wsm = waveReduceSum(lsum);
    if (lane == 0){ scratch[wvv] = wm; scratch[16+wvv] = wsm; }
    __syncthreads();
    float m_b = scratch[0], sumu = scratch[16];
    #pragma unroll
    for (int i = 1; i < 16; ++i){ m_b = fmaxf(m_b, scratch[i]); sumu += scratch[16+i]; }

    const float invTN2 = 1.0f / 67108.864f;   // 1/(T*N*N)
    float le = 0.f;
    #pragma unroll
    for (int t = 0; t < 16; ++t){
        float ex = __expf((uval[t] - m_b) * invTN2);
        if (is_auto){
            bool valid = (t > 8) || ((t == 8) && !j0);
            if (valid) le += ex;
        } else {
            bool inv = (t == 8) && j0;
            if (!inv) le += ((t == 0 && j0) ? 2.f : 1.f) * ex;
        }
    }
    float wle = waveReduceSum(le);
    if (lane == 0) scratch[32+wvv] = wle;
    __syncthreads();
    if (tid == 0){
        float sb2 = 0.f;
        #pragma unroll
        for (int i = 0; i < 16; ++i) sb2 += scratch[32+i];
        rec[rec_idx] = make_float4(m_b, sumu, sb2, 0.f);
    }
}

// Merge 528 records -> 7 outputs. Autos at rec[0..31], cross at rec[32..527].
__global__ __launch_bounds__(256) void final_kernel(const float4* __restrict__ rec,
                                                    float* __restrict__ out) {
    __shared__ float smA[256], smC[256];
    __shared__ double sS[256], sA[256], sC[256];
    const int tid = threadIdx.x;

    float mA = 0.f, mC = 0.f;
    for (int r = tid; r < NPAIR; r += 256){
        float mx = rec[r].x;
        if (r < M_WAVE) mA = fmaxf(mA, mx); else mC = fmaxf(mC, mx);
    }
    smA[tid] = mA; smC[tid] = mC;
    __syncthreads();
    for (int s = 128; s > 0; s >>= 1){
        if (tid < s){ smA[tid]=fmaxf(smA[tid],smA[tid+s]); smC[tid]=fmaxf(smC[tid],smC[tid+s]); }
        __syncthreads();
    }
    const float maxA_g = smA[0], maxC_g = smC[0];
    const float Mall = fmaxf(maxA_g, maxC_g);

    const float invTN2f = 1.0f / 67108.864f;
    double S = 0.0, sumA = 0.0, sumC = 0.0;
    for (int r = tid; r < NPAIR; r += 256){
        float4 rv = rec[r];
        S += (double)rv.z * (double)__expf((rv.x - Mall)*invTN2f);
        if (r < M_WAVE) sumA += (double)rv.y; else sumC += (double)rv.y;
    }
    sS[tid]=S; sA[tid]=sumA; sC[tid]=sumC;
    __syncthreads();
    for (int s = 128; s > 0; s >>= 1){
        if (tid < s){ sS[tid]+=sS[tid+s]; sA[tid]+=sA[tid+s]; sC[tid]+=sC[tid+s]; }
        __syncthreads();
    }
    if (tid == 0){
        const double invN2 = 1.0/67108864.0;
        out[0] = (float)((double)Mall*invN2 + 1e-3*log(sS[0]));
        out[1] = (float)((double)Mall*invN2);
        out[2] = maxA_g;
        out[3] = maxC_g;
        out[4] = (float)((sA[0]+sC[0])*invN2);
        out[5] = (float)sA[0];
        out[6] = (float)sC[0];
    }
}

extern "C" void kernel_launch(void* const* d_in, const int* in_sizes, int n_in,
                              void* d_out, int out_size, void* d_ws, size_t ws_size,
                              hipStream_t stream) {
    (void)in_sizes; (void)n_in; (void)out_size; (void)ws_size;
    const float* x = (const float*)d_in[0];
    float* out = (float*)d_out;

    float2* spec = (float2*)d_ws;
    float4* rec = (float4*)((char*)d_ws + (size_t)M_WAVE * FFT_N * sizeof(float2));

    fwd_fft_kernel<<<128, 256, 0, stream>>>(x, spec);
    pair_kernel<<<NPAIR, THREADS, 0, stream>>>(spec, rec);
    final_kernel<<<1, 256, 0, stream>>>(rec, out);
}